// Round 14
// baseline (258.987 us; speedup 1.0000x reference)
//
#include <hip/hip_runtime.h>

#define CC 64
#define HH 256
#define WW 256
#define SROW 140   // stage-A LDS row stride (dwords)
#define BROW 76    // k_keff LDS row stride

// 1x4 e12 conv at stride BROW: 5 rows x 3 aligned float4.
__device__ __forceinline__ void conv1x4_e12B(const float* __restrict__ rb,
                                             const float* __restrict__ w,
                                             float bv, float a[4])
{
#pragma unroll
    for (int j = 0; j < 4; j++) a[j] = bv;
#pragma unroll
    for (int ir = 0; ir < 5; ir++) {
        const float* s = rb + ir * BROW;
        float4 A = *(const float4*)s;
        float4 B = *(const float4*)(s + 4);
        float4 C = *(const float4*)(s + 8);
        float e[12] = {A.x, A.y, A.z, A.w, B.x, B.y, B.z, B.w,
                       C.x, C.y, C.z, C.w};
#pragma unroll
        for (int kx = 0; kx < 5; kx++) {
            const float wv = w[ir * 5 + kx];
#pragma unroll
            for (int j = 0; j < 4; j++) a[j] += e[j + kx + 2] * wv;
        }
    }
}

// 4x4 e12 conv core (k_dyn): reads 8 rows x 3 aligned float4 at rb + ir*SS.
template<int SS>
__device__ __forceinline__ void conv4x4_e12(const float* __restrict__ rb,
                                            const float* __restrict__ w,
                                            float bv, float a[4][4])
{
#pragma unroll
    for (int i = 0; i < 4; i++)
#pragma unroll
        for (int j = 0; j < 4; j++) a[i][j] = bv;
#pragma unroll
    for (int ir = 0; ir < 8; ir++) {
        const float* s = rb + ir * SS;
        float4 A = *(const float4*)s;
        float4 B = *(const float4*)(s + 4);
        float4 C = *(const float4*)(s + 8);
        float e[12] = {A.x, A.y, A.z, A.w, B.x, B.y, B.z, B.w,
                       C.x, C.y, C.z, C.w};
#pragma unroll
        for (int i = 0; i < 4; i++) {
            const int ky = ir - i;
            if (ky >= 0 && ky < 5) {
#pragma unroll
                for (int kx = 0; kx < 5; kx++) {
                    const float wv = w[ky * 5 + kx];
#pragma unroll
                    for (int j = 0; j < 4; j++) a[i][j] += e[j + kx + 2] * wv;
                }
            }
        }
    }
}

// 4x8 e16 conv core (k_a): reads 8 rows x 4 aligned float4 at rb + ir*SROW.
// e[m] <-> out-col-base-4+m; tap for (i,j,kx): e[j+kx+2], ky = ir-i.
__device__ __forceinline__ void conv4x8_e16(const float* __restrict__ rb,
                                            const float* __restrict__ w,
                                            float bv, float a[4][8])
{
#pragma unroll
    for (int i = 0; i < 4; i++)
#pragma unroll
        for (int j = 0; j < 8; j++) a[i][j] = bv;
#pragma unroll
    for (int ir = 0; ir < 8; ir++) {
        const float* s = rb + ir * SROW;
        float e[16];
#pragma unroll
        for (int m = 0; m < 4; m++) {
            float4 t = *(const float4*)(s + 4 * m);
            e[4 * m] = t.x; e[4 * m + 1] = t.y; e[4 * m + 2] = t.z; e[4 * m + 3] = t.w;
        }
#pragma unroll
        for (int i = 0; i < 4; i++) {
            const int ky = ir - i;
            if (ky >= 0 && ky < 5) {
#pragma unroll
                for (int kx = 0; kx < 5; kx++) {
                    const float wv = w[ky * 5 + kx];
#pragma unroll
                    for (int j = 0; j < 8; j++) a[i][j] += e[j + kx + 2] * wv;
                }
            }
        }
    }
}

// ---------------------------------------------------------------------------
// k_keff (unchanged, verified R13): linearize stage B into kq (pooled-space
// kernel, /4096, grouped 2x2 to match the conv3 register maxpool) and beta.
// ---------------------------------------------------------------------------
__global__ __launch_bounds__(512, 4) void k_keff(
    const float* __restrict__ w2, const float* __restrict__ b2,
    float* __restrict__ kq, float* __restrict__ beta)
{
    const int c = blockIdx.x;           // 0..63
    const int tid = threadIdx.x;
    __shared__ __align__(16) float sb[68 * BROW];
    __shared__ float red[16];

    for (int i = tid; i < 68 * 19; i += 512) {
        int r = i / 19, q = i % 19;
        int d = 4 * q;
        float4 v = make_float4(0.f, 0.f, 0.f, 0.f);
        if (r >= 2 && r < 66 && d >= 8 && d < 72)
            v = make_float4(1.f, 1.f, 1.f, 1.f);
        *(float4*)&sb[r * BROW + d] = v;
    }
    __syncthreads();

    const int r0 = tid >> 4;
    const int u = tid & 15;
    float S0 = 0.f, S1 = 0.f;

#pragma unroll
    for (int step = 0; step < 2; step++) {
        const int cv = 2 - step;
        float w[25];
#pragma unroll
        for (int k = 0; k < 25; k++) w[k] = w2[cv * CC * 25 + c * 25 + (24 - k)];
        float a0[4], a1[4];
        conv1x4_e12B(&sb[r0 * BROW + 4 * u + 4], w, 0.f, a0);
        conv1x4_e12B(&sb[(r0 + 32) * BROW + 4 * u + 4], w, 0.f, a1);
        __syncthreads();
        *(float4*)&sb[(r0 + 2) * BROW + 8 + 4 * u] = make_float4(a0[0], a0[1], a0[2], a0[3]);
        *(float4*)&sb[(r0 + 34) * BROW + 8 + 4 * u] = make_float4(a1[0], a1[1], a1[2], a1[3]);
        float s = a0[0] + a0[1] + a0[2] + a0[3] + a1[0] + a1[1] + a1[2] + a1[3];
        if (step == 0) S0 += s; else S1 += s;
        __syncthreads();
    }
    {
        float w[25];
#pragma unroll
        for (int k = 0; k < 25; k++) w[k] = w2[0 * CC * 25 + c * 25 + (24 - k)];
        float a0[4], a1[4];
        conv1x4_e12B(&sb[r0 * BROW + 4 * u + 4], w, 0.f, a0);
        conv1x4_e12B(&sb[(r0 + 32) * BROW + 4 * u + 4], w, 0.f, a1);
        __syncthreads();
        *(float4*)&sb[(r0 + 2) * BROW + 8 + 4 * u] = make_float4(a0[0], a0[1], a0[2], a0[3]);
        *(float4*)&sb[(r0 + 34) * BROW + 8 + 4 * u] = make_float4(a1[0], a1[1], a1[2], a1[3]);
        __syncthreads();
    }

    for (int i = tid; i < 1024; i += 512) {
        int v = i >> 5, uu = i & 31;
        float k00 = sb[(2 * v + 2) * BROW + 8 + 2 * uu];
        float k01 = sb[(2 * v + 2) * BROW + 8 + 2 * uu + 1];
        float k10 = sb[(2 * v + 3) * BROW + 8 + 2 * uu];
        float k11 = sb[(2 * v + 3) * BROW + 8 + 2 * uu + 1];
        *(float4*)&kq[((size_t)(c * 32 + v) * 32 + uu) * 4] =
            make_float4(k00 * (1.f / 4096.f), k01 * (1.f / 4096.f),
                        k10 * (1.f / 4096.f), k11 * (1.f / 4096.f));
    }

#pragma unroll
    for (int off = 32; off > 0; off >>= 1) {
        S0 += __shfl_down(S0, off);
        S1 += __shfl_down(S1, off);
    }
    if ((tid & 63) == 0) { red[tid >> 6] = S0; red[8 + (tid >> 6)] = S1; }
    __syncthreads();
    if (tid == 0) {
        float t0 = 0.f, t1 = 0.f;
#pragma unroll
        for (int k = 0; k < 8; k++) { t0 += red[k]; t1 += red[8 + k]; }
        beta[c] = (b2[0 * CC + c] * t1 + b2[1 * CC + c] * t0 +
                   4096.f * b2[2 * CC + c]) * (1.f / 4096.f);
    }
}

// ---------------------------------------------------------------------------
// k_a: HALF-plane per block. 1024 blocks x 512 thr, 76x140 LDS (42.6 KB ->
// 3 blocks/CU, 24 waves). Buffer row r = pooled row R0-6+r (r 0..75);
// col j at dword 8+j; dwords 0..7/136..139 zeroed once (never rewritten).
// In-place: conv1 (18x16 4x8-tiles) writes rows +2; conv2 (17x16) rows +2;
// conv3 (16x16) -> register 2x2 maxpool -> dot kq -> part[plane*2+by].
// Out-of-image output rows predicated to zero (cols always in-image).
// ---------------------------------------------------------------------------
__global__ __launch_bounds__(512, 6) void k_a(
    const float* __restrict__ x, const float* __restrict__ w1,
    const float* __restrict__ b1, const float* __restrict__ kq,
    float* __restrict__ part)
{
    const int by = blockIdx.x;             // 0,1
    const int plane = blockIdx.y;          // b*64 + c
    const int c = plane & 63;
    const int R0 = by * 64;                // pooled row base of this half
    const int tid = threadIdx.x;

    __shared__ __align__(16) float sb[76 * SROW];
    __shared__ float red[8];

    const float* xp = x + (size_t)plane * HH * WW;

    // fill: avgpool(2x2) of x; 76 rows x 35 f4 = 2660 items.
#pragma unroll
    for (int k = 0; k < 6; k++) {
        int i = tid + k * 512;
        if (i < 76 * 35) {
            int r = i / 35, f = i % 35;
            int d = 4 * f;
            float4 v = make_float4(0.f, 0.f, 0.f, 0.f);
            int pr = R0 - 6 + r;           // pooled row
            if (d >= 8 && d < 136 && (unsigned)pr < 128u) {
                int xc = 2 * (d - 8);
                const float* p0 = xp + (size_t)(2 * pr) * WW + xc;
                const float* p1 = p0 + WW;
                float4 a0 = *(const float4*)p0;
                float4 a1 = *(const float4*)(p0 + 4);
                float4 b0 = *(const float4*)p1;
                float4 b1v = *(const float4*)(p1 + 4);
                v.x = 0.25f * (a0.x + a0.y + b0.x + b0.y);
                v.y = 0.25f * (a0.z + a0.w + b0.z + b0.w);
                v.z = 0.25f * (a1.x + a1.y + b1v.x + b1v.y);
                v.w = 0.25f * (a1.z + a1.w + b1v.z + b1v.w);
            }
            *(float4*)&sb[r * SROW + d] = v;
        }
    }
    __syncthreads();

    const int v = tid >> 4, u = tid & 15;   // row-tile, col-tile(8-wide)

    // conv1: 18x16 = 288 tiles; out pooled rows R0-4+4v+i, cols 8u..8u+7.
    {
        float w[25];
#pragma unroll
        for (int k = 0; k < 25; k++) w[k] = w1[0 * CC * 25 + c * 25 + k];  // SGPR
        const float bv = b1[0 * CC + c];
        const bool act = tid < 288;
        float a[4][8];
        if (act) {
            conv4x8_e16(&sb[(4 * v) * SROW + 4 + 8 * u], w, bv, a);
#pragma unroll
            for (int i = 0; i < 4; i++) {
                int gi = R0 - 4 + 4 * v + i;
                if ((unsigned)gi >= 128u) {
#pragma unroll
                    for (int j = 0; j < 8; j++) a[i][j] = 0.f;
                }
            }
        }
        __syncthreads();
        if (act) {
#pragma unroll
            for (int i = 0; i < 4; i++) {
                float* row = &sb[(2 + 4 * v + i) * SROW + 8 + 8 * u];
                *(float4*)row = make_float4(a[i][0], a[i][1], a[i][2], a[i][3]);
                *(float4*)(row + 4) = make_float4(a[i][4], a[i][5], a[i][6], a[i][7]);
            }
        }
        __syncthreads();
    }

    // conv2: 17x16 = 272 tiles; out rows R0-2+4v+i.
    {
        float w[25];
#pragma unroll
        for (int k = 0; k < 25; k++) w[k] = w1[1 * CC * 25 + c * 25 + k];
        const float bv = b1[1 * CC + c];
        const bool act = tid < 272;
        float a[4][8];
        if (act) {
            conv4x8_e16(&sb[(2 + 4 * v) * SROW + 4 + 8 * u], w, bv, a);
#pragma unroll
            for (int i = 0; i < 4; i++) {
                int gi = R0 - 2 + 4 * v + i;
                if ((unsigned)gi >= 128u) {
#pragma unroll
                    for (int j = 0; j < 8; j++) a[i][j] = 0.f;
                }
            }
        }
        __syncthreads();
        if (act) {
#pragma unroll
            for (int i = 0; i < 4; i++) {
                float* row = &sb[(4 + 4 * v + i) * SROW + 8 + 8 * u];
                *(float4*)row = make_float4(a[i][0], a[i][1], a[i][2], a[i][3]);
                *(float4*)(row + 4) = make_float4(a[i][4], a[i][5], a[i][6], a[i][7]);
            }
        }
        __syncthreads();
    }

    // conv3: 16x16 = 256 tiles; out rows R0+4v+i (all in image) ->
    // register 2x2 maxpool -> dot with kq (two float4 entries).
    float partial = 0.f;
    if (tid < 256) {
        float w[25];
#pragma unroll
        for (int k = 0; k < 25; k++) w[k] = w1[2 * CC * 25 + c * 25 + k];
        const float bv = b1[2 * CC + c];
        float a[4][8];
        conv4x8_e16(&sb[(4 + 4 * v) * SROW + 4 + 8 * u], w, bv, a);
        // pooled 2x4 block at pooled rows R0/2+2v..+1, cols 4u..4u+3
        float m[2][4];
#pragma unroll
        for (int p = 0; p < 2; p++)
#pragma unroll
            for (int q = 0; q < 4; q++)
                m[p][q] = fmaxf(fmaxf(a[2 * p][2 * q], a[2 * p][2 * q + 1]),
                                fmaxf(a[2 * p + 1][2 * q], a[2 * p + 1][2 * q + 1]));
        const int V = (R0 >> 2) + v;        // kq row index
        const int U0 = 2 * u;
        float4 k0 = *(const float4*)&kq[((size_t)(c * 32 + V) * 32 + U0) * 4];
        float4 k1 = *(const float4*)&kq[((size_t)(c * 32 + V) * 32 + U0 + 1) * 4];
        partial = m[0][0] * k0.x + m[0][1] * k0.y + m[1][0] * k0.z + m[1][1] * k0.w
                + m[0][2] * k1.x + m[0][3] * k1.y + m[1][2] * k1.z + m[1][3] * k1.w;
    }
#pragma unroll
    for (int off = 32; off > 0; off >>= 1) partial += __shfl_down(partial, off);
    if ((tid & 63) == 0) red[tid >> 6] = partial;
    __syncthreads();
    if (tid == 0) {
        float t = 0.f;
#pragma unroll
        for (int k = 0; k < 8; k++) t += red[k];
        part[plane * 2 + by] = t;
    }
}

// ---------------------------------------------------------------------------
// k_kern: per-batch block assembles g[b,:] = beta + part halves in LDS,
// then kern[b,o] = dot(g[b,:], wk[o,:]) + bk[o].
// ---------------------------------------------------------------------------
__global__ __launch_bounds__(256) void k_kern(
    const float* __restrict__ part, const float* __restrict__ beta,
    const float* __restrict__ wk, const float* __restrict__ bk,
    float* __restrict__ kern)
{
    const int b = blockIdx.x;              // 0..7
    const int tid = threadIdx.x;
    __shared__ float sg[64];
    if (tid < 64) {
        int plane = b * 64 + tid;
        sg[tid] = beta[tid] + part[plane * 2] + part[plane * 2 + 1];
    }
    __syncthreads();
    for (int o = tid; o < 1600; o += 256) {
        float v = bk[o];
        const float* wp = wk + (size_t)o * 64;
#pragma unroll 8
        for (int k = 0; k < 64; k++) v += sg[k] * wp[k];
        kern[b * 1600 + o] = v;
    }
}

// ---------------------------------------------------------------------------
// k_dyn: dynamic depthwise conv 5x5, 64x64 tile, 4x4 outputs/thread.
// (At HBM roofline per R4/R13 analysis -- unchanged.)
// ---------------------------------------------------------------------------
__global__ __launch_bounds__(256) void k_dyn(
    const float* __restrict__ x, const float* __restrict__ kern,
    const float* __restrict__ bias, float* __restrict__ out)
{
    const int plane = blockIdx.z;
    const int tx = blockIdx.x, ty = blockIdx.y;
    const int tid = threadIdx.x;

    __shared__ __align__(16) float sx[68 * 76];

    const float* xp = x + (size_t)plane * HH * WW;
    const int R0 = ty * 64, C0 = tx * 64;

#pragma unroll
    for (int k = 0; k < 5; k++) {
        int i = tid + k * 256;
        if (i < 68 * 18) {
            int r = i / 18, q = i - r * 18;
            int gr = R0 - 2 + r;
            int gc = C0 - 4 + 4 * q;
            float4 v = make_float4(0.f, 0.f, 0.f, 0.f);
            if ((unsigned)gr < HH && (unsigned)gc < WW)
                v = *(const float4*)(xp + (size_t)gr * WW + gc);
            *(float4*)&sx[r * 76 + 4 * q] = v;
        }
    }

    float w[25];
#pragma unroll
    for (int k = 0; k < 25; k++) w[k] = kern[(size_t)plane * 25 + k];   // uniform
    const float bv = bias[plane & 63];

    __syncthreads();

    const int tr = (tid >> 4) * 4, tc = (tid & 15) * 4;
    float acc[4][4];
    conv4x4_e12<76>(&sx[tr * 76 + tc], w, bv, acc);

    float* op = out + (size_t)plane * HH * WW + (size_t)(R0 + tr) * WW + C0 + tc;
#pragma unroll
    for (int i = 0; i < 4; i++)
        *(float4*)(op + (size_t)i * WW) = make_float4(acc[i][0], acc[i][1], acc[i][2], acc[i][3]);
}

// ---------------------------------------------------------------------------
extern "C" void kernel_launch(void* const* d_in, const int* in_sizes, int n_in,
                              void* d_out, int out_size, void* d_ws, size_t ws_size,
                              hipStream_t stream)
{
    const float* x    = (const float*)d_in[0];
    const float* w1   = (const float*)d_in[1];
    const float* b1   = (const float*)d_in[2];
    const float* w2   = (const float*)d_in[3];
    const float* b2   = (const float*)d_in[4];
    const float* wk   = (const float*)d_in[5];
    const float* bk   = (const float*)d_in[6];
    const float* bias = (const float*)d_in[7];
    float* out = (float*)d_out;

    float* ws   = (float*)d_ws;
    float* kq   = ws;                       // 262144
    float* beta = ws + 262144;              // 64
    float* part = ws + 262208;              // 1024
    float* kern = ws + 263232;              // 12800

    k_keff<<<dim3(64), 512, 0, stream>>>(w2, b2, kq, beta);
    k_a<<<dim3(2, 512), 512, 0, stream>>>(x, w1, b1, kq, part);
    k_kern<<<dim3(8), 256, 0, stream>>>(part, beta, wk, bk, kern);
    k_dyn<<<dim3(4, 4, 512), 256, 0, stream>>>(x, kern, bias, out);
}

// Round 15
// 139.477 us; speedup vs baseline: 1.8568x; 1.8568x over previous
//
#include <hip/hip_runtime.h>

#define CC 64
#define HH 256
#define WW 256
#define SROW 140   // stage-A LDS row stride (dwords)
#define BROW 76    // k_keff LDS row stride

// 1x4 e12 conv at stride BROW: 5 rows x 3 aligned float4.
__device__ __forceinline__ void conv1x4_e12B(const float* __restrict__ rb,
                                             const float* __restrict__ w,
                                             float bv, float a[4])
{
#pragma unroll
    for (int j = 0; j < 4; j++) a[j] = bv;
#pragma unroll
    for (int ir = 0; ir < 5; ir++) {
        const float* s = rb + ir * BROW;
        float4 A = *(const float4*)s;
        float4 B = *(const float4*)(s + 4);
        float4 C = *(const float4*)(s + 8);
        float e[12] = {A.x, A.y, A.z, A.w, B.x, B.y, B.z, B.w,
                       C.x, C.y, C.z, C.w};
#pragma unroll
        for (int kx = 0; kx < 5; kx++) {
            const float wv = w[ir * 5 + kx];
#pragma unroll
            for (int j = 0; j < 4; j++) a[j] += e[j + kx + 2] * wv;
        }
    }
}

// 4x4 e12 conv core: reads 8 rows x 3 aligned float4 at rb + ir*SS.
// ONE 16-float accumulator set per thread -- spill-free (32 VGPR, R12/R13).
template<int SS>
__device__ __forceinline__ void conv4x4_e12(const float* __restrict__ rb,
                                            const float* __restrict__ w,
                                            float bv, float a[4][4])
{
#pragma unroll
    for (int i = 0; i < 4; i++)
#pragma unroll
        for (int j = 0; j < 4; j++) a[i][j] = bv;
#pragma unroll
    for (int ir = 0; ir < 8; ir++) {
        const float* s = rb + ir * SS;
        float4 A = *(const float4*)s;
        float4 B = *(const float4*)(s + 4);
        float4 C = *(const float4*)(s + 8);
        float e[12] = {A.x, A.y, A.z, A.w, B.x, B.y, B.z, B.w,
                       C.x, C.y, C.z, C.w};
#pragma unroll
        for (int i = 0; i < 4; i++) {
            const int ky = ir - i;
            if (ky >= 0 && ky < 5) {
#pragma unroll
                for (int kx = 0; kx < 5; kx++) {
                    const float wv = w[ky * 5 + kx];
#pragma unroll
                    for (int j = 0; j < 4; j++) a[i][j] += e[j + kx + 2] * wv;
                }
            }
        }
    }
}

// ---------------------------------------------------------------------------
// k_keff (verified R13): linearize stage B. kq[c][V][U][4] = 2x2 group of
// K_eff = W1^T W2^T W3^T 1 / 4096; beta from bias sums.
// ---------------------------------------------------------------------------
__global__ __launch_bounds__(512, 4) void k_keff(
    const float* __restrict__ w2, const float* __restrict__ b2,
    float* __restrict__ kq, float* __restrict__ beta)
{
    const int c = blockIdx.x;           // 0..63
    const int tid = threadIdx.x;
    __shared__ __align__(16) float sb[68 * BROW];
    __shared__ float red[16];

    for (int i = tid; i < 68 * 19; i += 512) {
        int r = i / 19, q = i % 19;
        int d = 4 * q;
        float4 v = make_float4(0.f, 0.f, 0.f, 0.f);
        if (r >= 2 && r < 66 && d >= 8 && d < 72)
            v = make_float4(1.f, 1.f, 1.f, 1.f);
        *(float4*)&sb[r * BROW + d] = v;
    }
    __syncthreads();

    const int r0 = tid >> 4;
    const int u = tid & 15;
    float S0 = 0.f, S1 = 0.f;

#pragma unroll
    for (int step = 0; step < 2; step++) {
        const int cv = 2 - step;
        float w[25];
#pragma unroll
        for (int k = 0; k < 25; k++) w[k] = w2[cv * CC * 25 + c * 25 + (24 - k)];
        float a0[4], a1[4];
        conv1x4_e12B(&sb[r0 * BROW + 4 * u + 4], w, 0.f, a0);
        conv1x4_e12B(&sb[(r0 + 32) * BROW + 4 * u + 4], w, 0.f, a1);
        __syncthreads();
        *(float4*)&sb[(r0 + 2) * BROW + 8 + 4 * u] = make_float4(a0[0], a0[1], a0[2], a0[3]);
        *(float4*)&sb[(r0 + 34) * BROW + 8 + 4 * u] = make_float4(a1[0], a1[1], a1[2], a1[3]);
        float s = a0[0] + a0[1] + a0[2] + a0[3] + a1[0] + a1[1] + a1[2] + a1[3];
        if (step == 0) S0 += s; else S1 += s;
        __syncthreads();
    }
    {
        float w[25];
#pragma unroll
        for (int k = 0; k < 25; k++) w[k] = w2[0 * CC * 25 + c * 25 + (24 - k)];
        float a0[4], a1[4];
        conv1x4_e12B(&sb[r0 * BROW + 4 * u + 4], w, 0.f, a0);
        conv1x4_e12B(&sb[(r0 + 32) * BROW + 4 * u + 4], w, 0.f, a1);
        __syncthreads();
        *(float4*)&sb[(r0 + 2) * BROW + 8 + 4 * u] = make_float4(a0[0], a0[1], a0[2], a0[3]);
        *(float4*)&sb[(r0 + 34) * BROW + 8 + 4 * u] = make_float4(a1[0], a1[1], a1[2], a1[3]);
        __syncthreads();
    }

    for (int i = tid; i < 1024; i += 512) {
        int v = i >> 5, uu = i & 31;
        float k00 = sb[(2 * v + 2) * BROW + 8 + 2 * uu];
        float k01 = sb[(2 * v + 2) * BROW + 8 + 2 * uu + 1];
        float k10 = sb[(2 * v + 3) * BROW + 8 + 2 * uu];
        float k11 = sb[(2 * v + 3) * BROW + 8 + 2 * uu + 1];
        *(float4*)&kq[((size_t)(c * 32 + v) * 32 + uu) * 4] =
            make_float4(k00 * (1.f / 4096.f), k01 * (1.f / 4096.f),
                        k10 * (1.f / 4096.f), k11 * (1.f / 4096.f));
    }

#pragma unroll
    for (int off = 32; off > 0; off >>= 1) {
        S0 += __shfl_down(S0, off);
        S1 += __shfl_down(S1, off);
    }
    if ((tid & 63) == 0) { red[tid >> 6] = S0; red[8 + (tid >> 6)] = S1; }
    __syncthreads();
    if (tid == 0) {
        float t0 = 0.f, t1 = 0.f;
#pragma unroll
        for (int k = 0; k < 8; k++) { t0 += red[k]; t1 += red[8 + k]; }
        beta[c] = (b2[0 * CC + c] * t1 + b2[1 * CC + c] * t0 +
                   4096.f * b2[2 * CC + c]) * (1.f / 4096.f);
    }
}

// ---------------------------------------------------------------------------
// k_a: HALF-plane, 1024 blocks x 1024 thr, 4x4 tiles (spill-free core).
// LDS 76x140 (42.6 KB); 2 blocks/CU (wave-limited), 2 rounds -> stagger.
// Buffer row r = pooled row R0-6+r; col j at dword 8+j; margins zeroed once.
// conv1: 18x32=576 tiles; conv2 17x32=544; conv3 16x32=512 -> reg 2x2
// maxpool -> dot kq[c][16*by+v][u] -> part[plane*2+by].
// ---------------------------------------------------------------------------
__global__ __launch_bounds__(1024, 8) void k_a(
    const float* __restrict__ x, const float* __restrict__ w1,
    const float* __restrict__ b1, const float* __restrict__ kq,
    float* __restrict__ part)
{
    const int by = blockIdx.x;             // 0,1
    const int plane = blockIdx.y;          // b*64 + c
    const int c = plane & 63;
    const int R0 = by * 64;                // pooled row base of this half
    const int tid = threadIdx.x;

    __shared__ __align__(16) float sb[76 * SROW];
    __shared__ float red[16];

    const float* xp = x + (size_t)plane * HH * WW;

    // fill: avgpool(2x2) of x; 76 rows x 35 f4 = 2660 items (R14-verified).
#pragma unroll
    for (int k = 0; k < 3; k++) {
        int i = tid + k * 1024;
        if (i < 76 * 35) {
            int r = i / 35, f = i % 35;
            int d = 4 * f;
            float4 v = make_float4(0.f, 0.f, 0.f, 0.f);
            int pr = R0 - 6 + r;           // pooled row
            if (d >= 8 && d < 136 && (unsigned)pr < 128u) {
                int xc = 2 * (d - 8);
                const float* p0 = xp + (size_t)(2 * pr) * WW + xc;
                const float* p1 = p0 + WW;
                float4 a0 = *(const float4*)p0;
                float4 a1 = *(const float4*)(p0 + 4);
                float4 b0 = *(const float4*)p1;
                float4 b1v = *(const float4*)(p1 + 4);
                v.x = 0.25f * (a0.x + a0.y + b0.x + b0.y);
                v.y = 0.25f * (a0.z + a0.w + b0.z + b0.w);
                v.z = 0.25f * (a1.x + a1.y + b1v.x + b1v.y);
                v.w = 0.25f * (a1.z + a1.w + b1v.z + b1v.w);
            }
            *(float4*)&sb[r * SROW + d] = v;
        }
    }
    __syncthreads();

    const int v = tid >> 5, u = tid & 31;   // row-tile 0..31, col-tile (4-wide)

    // conv1: v<18; read rows 4v..; out pooled rows R0-4+4v+i -> buf rows 2+4v+i
    {
        float w[25];
#pragma unroll
        for (int k = 0; k < 25; k++) w[k] = w1[0 * CC * 25 + c * 25 + k];  // SGPR
        const float bv = b1[0 * CC + c];
        const bool act = v < 18;
        float a[4][4];
        if (act) {
            conv4x4_e12<SROW>(&sb[(4 * v) * SROW + 4 * u + 4], w, bv, a);
#pragma unroll
            for (int i = 0; i < 4; i++) {
                int gi = R0 - 4 + 4 * v + i;
                if ((unsigned)gi >= 128u) {
#pragma unroll
                    for (int j = 0; j < 4; j++) a[i][j] = 0.f;
                }
            }
        }
        __syncthreads();
        if (act) {
#pragma unroll
            for (int i = 0; i < 4; i++)
                *(float4*)&sb[(2 + 4 * v + i) * SROW + 8 + 4 * u] =
                    make_float4(a[i][0], a[i][1], a[i][2], a[i][3]);
        }
        __syncthreads();
    }

    // conv2: v<17; read rows 2+4v; out rows R0-2+4v+i -> buf rows 4+4v+i
    {
        float w[25];
#pragma unroll
        for (int k = 0; k < 25; k++) w[k] = w1[1 * CC * 25 + c * 25 + k];
        const float bv = b1[1 * CC + c];
        const bool act = v < 17;
        float a[4][4];
        if (act) {
            conv4x4_e12<SROW>(&sb[(2 + 4 * v) * SROW + 4 * u + 4], w, bv, a);
#pragma unroll
            for (int i = 0; i < 4; i++) {
                int gi = R0 - 2 + 4 * v + i;
                if ((unsigned)gi >= 128u) {
#pragma unroll
                    for (int j = 0; j < 4; j++) a[i][j] = 0.f;
                }
            }
        }
        __syncthreads();
        if (act) {
#pragma unroll
            for (int i = 0; i < 4; i++)
                *(float4*)&sb[(4 + 4 * v + i) * SROW + 8 + 4 * u] =
                    make_float4(a[i][0], a[i][1], a[i][2], a[i][3]);
        }
        __syncthreads();
    }

    // conv3: v<16; read rows 4+4v; out rows R0+4v+i (in-image) ->
    // register 2x2 maxpool -> dot with kq[c][16*by+v][u].
    float partial = 0.f;
    if (v < 16) {
        float w[25];
#pragma unroll
        for (int k = 0; k < 25; k++) w[k] = w1[2 * CC * 25 + c * 25 + k];
        const float bv = b1[2 * CC + c];
        float a[4][4];
        conv4x4_e12<SROW>(&sb[(4 + 4 * v) * SROW + 4 * u + 4], w, bv, a);
        float m00 = fmaxf(fmaxf(a[0][0], a[0][1]), fmaxf(a[1][0], a[1][1]));
        float m01 = fmaxf(fmaxf(a[0][2], a[0][3]), fmaxf(a[1][2], a[1][3]));
        float m10 = fmaxf(fmaxf(a[2][0], a[2][1]), fmaxf(a[3][0], a[3][1]));
        float m11 = fmaxf(fmaxf(a[2][2], a[2][3]), fmaxf(a[3][2], a[3][3]));
        const int V = 16 * by + v;
        float4 kk = *(const float4*)&kq[((size_t)(c * 32 + V) * 32 + u) * 4];
        partial = m00 * kk.x + m01 * kk.y + m10 * kk.z + m11 * kk.w;
    }
#pragma unroll
    for (int off = 32; off > 0; off >>= 1) partial += __shfl_down(partial, off);
    if ((tid & 63) == 0) red[tid >> 6] = partial;
    __syncthreads();
    if (tid == 0) {
        float t = 0.f;
#pragma unroll
        for (int k = 0; k < 16; k++) t += red[k];
        part[plane * 2 + by] = t;
    }
}

// ---------------------------------------------------------------------------
// k_kern (verified R14): g[b,:] = beta + part halves; then the 1600-dot.
// ---------------------------------------------------------------------------
__global__ __launch_bounds__(256) void k_kern(
    const float* __restrict__ part, const float* __restrict__ beta,
    const float* __restrict__ wk, const float* __restrict__ bk,
    float* __restrict__ kern)
{
    const int b = blockIdx.x;              // 0..7
    const int tid = threadIdx.x;
    __shared__ float sg[64];
    if (tid < 64) {
        int plane = b * 64 + tid;
        sg[tid] = beta[tid] + part[plane * 2] + part[plane * 2 + 1];
    }
    __syncthreads();
    for (int o = tid; o < 1600; o += 256) {
        float v = bk[o];
        const float* wp = wk + (size_t)o * 64;
#pragma unroll 8
        for (int k = 0; k < 64; k++) v += sg[k] * wp[k];
        kern[b * 1600 + o] = v;
    }
}

// ---------------------------------------------------------------------------
// k_dyn: dynamic depthwise conv 5x5 (at HBM roofline -- unchanged).
// ---------------------------------------------------------------------------
__global__ __launch_bounds__(256) void k_dyn(
    const float* __restrict__ x, const float* __restrict__ kern,
    const float* __restrict__ bias, float* __restrict__ out)
{
    const int plane = blockIdx.z;
    const int tx = blockIdx.x, ty = blockIdx.y;
    const int tid = threadIdx.x;

    __shared__ __align__(16) float sx[68 * 76];

    const float* xp = x + (size_t)plane * HH * WW;
    const int R0 = ty * 64, C0 = tx * 64;

#pragma unroll
    for (int k = 0; k < 5; k++) {
        int i = tid + k * 256;
        if (i < 68 * 18) {
            int r = i / 18, q = i - r * 18;
            int gr = R0 - 2 + r;
            int gc = C0 - 4 + 4 * q;
            float4 v = make_float4(0.f, 0.f, 0.f, 0.f);
            if ((unsigned)gr < HH && (unsigned)gc < WW)
                v = *(const float4*)(xp + (size_t)gr * WW + gc);
            *(float4*)&sx[r * 76 + 4 * q] = v;
        }
    }

    float w[25];
#pragma unroll
    for (int k = 0; k < 25; k++) w[k] = kern[(size_t)plane * 25 + k];   // uniform
    const float bv = bias[plane & 63];

    __syncthreads();

    const int tr = (tid >> 4) * 4, tc = (tid & 15) * 4;
    float acc[4][4];
    conv4x4_e12<76>(&sx[tr * 76 + tc], w, bv, acc);

    float* op = out + (size_t)plane * HH * WW + (size_t)(R0 + tr) * WW + C0 + tc;
#pragma unroll
    for (int i = 0; i < 4; i++)
        *(float4*)(op + (size_t)i * WW) = make_float4(acc[i][0], acc[i][1], acc[i][2], acc[i][3]);
}

// ---------------------------------------------------------------------------
extern "C" void kernel_launch(void* const* d_in, const int* in_sizes, int n_in,
                              void* d_out, int out_size, void* d_ws, size_t ws_size,
                              hipStream_t stream)
{
    const float* x    = (const float*)d_in[0];
    const float* w1   = (const float*)d_in[1];
    const float* b1   = (const float*)d_in[2];
    const float* w2   = (const float*)d_in[3];
    const float* b2   = (const float*)d_in[4];
    const float* wk   = (const float*)d_in[5];
    const float* bk   = (const float*)d_in[6];
    const float* bias = (const float*)d_in[7];
    float* out = (float*)d_out;

    float* ws   = (float*)d_ws;
    float* kq   = ws;                       // 262144
    float* beta = ws + 262144;              // 64
    float* part = ws + 262208;              // 1024
    float* kern = ws + 263232;              // 12800

    k_keff<<<dim3(64), 512, 0, stream>>>(w2, b2, kq, beta);
    k_a<<<dim3(2, 512), 1024, 0, stream>>>(x, w1, b1, kq, part);
    k_kern<<<dim3(8), 256, 0, stream>>>(part, beta, wk, bk, kern);
    k_dyn<<<dim3(4, 4, 512), 256, 0, stream>>>(x, kern, bias, out);
}

// Round 16
// 114.540 us; speedup vs baseline: 2.2611x; 1.2177x over previous
//
#include <hip/hip_runtime.h>

#define CC 64
#define HH 256
#define WW 256
#define SROW 140   // stage-A LDS row stride (dwords)
#define BROW 76    // k_keff LDS row stride

// 4x4 e12 conv core: reads 8 rows x 3 aligned float4 at rb + ir*SS.
// ONE 16-float accumulator set per thread -- spill-free (32 VGPR).
template<int SS>
__device__ __forceinline__ void conv4x4_e12(const float* __restrict__ rb,
                                            const float* __restrict__ w,
                                            float bv, float a[4][4])
{
#pragma unroll
    for (int i = 0; i < 4; i++)
#pragma unroll
        for (int j = 0; j < 4; j++) a[i][j] = bv;
#pragma unroll
    for (int ir = 0; ir < 8; ir++) {
        const float* s = rb + ir * SS;
        float4 A = *(const float4*)s;
        float4 B = *(const float4*)(s + 4);
        float4 C = *(const float4*)(s + 8);
        float e[12] = {A.x, A.y, A.z, A.w, B.x, B.y, B.z, B.w,
                       C.x, C.y, C.z, C.w};
#pragma unroll
        for (int i = 0; i < 4; i++) {
            const int ky = ir - i;
            if (ky >= 0 && ky < 5) {
#pragma unroll
                for (int kx = 0; kx < 5; kx++) {
                    const float wv = w[ky * 5 + kx];
#pragma unroll
                    for (int j = 0; j < 4; j++) a[i][j] += e[j + kx + 2] * wv;
                }
            }
        }
    }
}

// 1x4 e12 conv at stride BROW: 5 rows x 3 aligned float4.
__device__ __forceinline__ void conv1x4_e12B(const float* __restrict__ rb,
                                             const float* __restrict__ w,
                                             float bv, float a[4])
{
#pragma unroll
    for (int j = 0; j < 4; j++) a[j] = bv;
#pragma unroll
    for (int ir = 0; ir < 5; ir++) {
        const float* s = rb + ir * BROW;
        float4 A = *(const float4*)s;
        float4 B = *(const float4*)(s + 4);
        float4 C = *(const float4*)(s + 8);
        float e[12] = {A.x, A.y, A.z, A.w, B.x, B.y, B.z, B.w,
                       C.x, C.y, C.z, C.w};
#pragma unroll
        for (int kx = 0; kx < 5; kx++) {
            const float wv = w[ir * 5 + kx];
#pragma unroll
            for (int j = 0; j < 4; j++) a[j] += e[j + kx + 2] * wv;
        }
    }
}

// ---------------------------------------------------------------------------
// k_keff: per channel c, linearize stage B. g = <K_eff, t2> + beta where
// K_eff = W1^T W2^T W3^T 1 / 4096 (flipped-kernel zero-padded conv chain on a
// ones image; Wi = stage-B conv i) and
// beta = (b2[0]*sum(u2) + b2[1]*sum(u1) + 4096*b2[2]) / 4096.
// kq layout: kq[c][v][u][4] = {K[2v][2u],K[2v][2u+1],K[2v+1][2u],K[2v+1][2u+1]}/4096
// matching k_a's conv3 tile (v,u) register maxpool.  [verified R13]
// ---------------------------------------------------------------------------
__global__ __launch_bounds__(512, 4) void k_keff(
    const float* __restrict__ w2, const float* __restrict__ b2,
    float* __restrict__ kq, float* __restrict__ beta)
{
    const int c = blockIdx.x;           // 0..63
    const int tid = threadIdx.x;
    __shared__ __align__(16) float sb[68 * BROW];
    __shared__ float red[16];

    // init: ones interior (rows 2..65, dwords 8..71), zero margins
    for (int i = tid; i < 68 * 19; i += 512) {
        int r = i / 19, q = i % 19;
        int d = 4 * q;
        float4 v = make_float4(0.f, 0.f, 0.f, 0.f);
        if (r >= 2 && r < 66 && d >= 8 && d < 72)
            v = make_float4(1.f, 1.f, 1.f, 1.f);
        *(float4*)&sb[r * BROW + d] = v;
    }
    __syncthreads();

    const int r0 = tid >> 4;            // 0..31 (strips r0 and r0+32)
    const int u = tid & 15;
    float S0 = 0.f, S1 = 0.f;           // sum(u1), sum(u2)

#pragma unroll
    for (int step = 0; step < 2; step++) {
        const int cv = 2 - step;        // w2[2] then w2[1], flipped
        float w[25];
#pragma unroll
        for (int k = 0; k < 25; k++) w[k] = w2[cv * CC * 25 + c * 25 + (24 - k)];
        float a0[4], a1[4];
        conv1x4_e12B(&sb[r0 * BROW + 4 * u + 4], w, 0.f, a0);
        conv1x4_e12B(&sb[(r0 + 32) * BROW + 4 * u + 4], w, 0.f, a1);
        __syncthreads();
        *(float4*)&sb[(r0 + 2) * BROW + 8 + 4 * u] = make_float4(a0[0], a0[1], a0[2], a0[3]);
        *(float4*)&sb[(r0 + 34) * BROW + 8 + 4 * u] = make_float4(a1[0], a1[1], a1[2], a1[3]);
        float s = a0[0] + a0[1] + a0[2] + a0[3] + a1[0] + a1[1] + a1[2] + a1[3];
        if (step == 0) S0 += s; else S1 += s;
        __syncthreads();
    }

    // final conv with flipped w2[0] -> K, back into sb
    {
        float w[25];
#pragma unroll
        for (int k = 0; k < 25; k++) w[k] = w2[0 * CC * 25 + c * 25 + (24 - k)];
        float a0[4], a1[4];
        conv1x4_e12B(&sb[r0 * BROW + 4 * u + 4], w, 0.f, a0);
        conv1x4_e12B(&sb[(r0 + 32) * BROW + 4 * u + 4], w, 0.f, a1);
        __syncthreads();
        *(float4*)&sb[(r0 + 2) * BROW + 8 + 4 * u] = make_float4(a0[0], a0[1], a0[2], a0[3]);
        *(float4*)&sb[(r0 + 34) * BROW + 8 + 4 * u] = make_float4(a1[0], a1[1], a1[2], a1[3]);
        __syncthreads();
    }

    // regroup into kq (2x2 per entry), scaled 1/4096
    for (int i = tid; i < 1024; i += 512) {
        int v = i >> 5, uu = i & 31;
        float k00 = sb[(2 * v + 2) * BROW + 8 + 2 * uu];
        float k01 = sb[(2 * v + 2) * BROW + 8 + 2 * uu + 1];
        float k10 = sb[(2 * v + 3) * BROW + 8 + 2 * uu];
        float k11 = sb[(2 * v + 3) * BROW + 8 + 2 * uu + 1];
        *(float4*)&kq[((size_t)(c * 32 + v) * 32 + uu) * 4] =
            make_float4(k00 * (1.f / 4096.f), k01 * (1.f / 4096.f),
                        k10 * (1.f / 4096.f), k11 * (1.f / 4096.f));
    }

    // reduce S0,S1 -> beta
#pragma unroll
    for (int off = 32; off > 0; off >>= 1) {
        S0 += __shfl_down(S0, off);
        S1 += __shfl_down(S1, off);
    }
    if ((tid & 63) == 0) { red[tid >> 6] = S0; red[8 + (tid >> 6)] = S1; }
    __syncthreads();
    if (tid == 0) {
        float t0 = 0.f, t1 = 0.f;
#pragma unroll
        for (int k = 0; k < 8; k++) { t0 += red[k]; t1 += red[8 + k]; }
        beta[c] = (b2[0 * CC + c] * t1 + b2[1 * CC + c] * t0 +
                   4096.f * b2[2 * CC + c]) * (1.f / 4096.f);
    }
}

// ---------------------------------------------------------------------------
// k_a: avgpool + conv1 + conv2 + conv3 + reg-maxpool + <.,kq> dot -> g.
// 1024 thr, one block/plane, 2 blocks/CU. A-buffer 132x140 (73.9 KB).
// Row r = pooled row r-2; col j at dword 8+j; margins zeroed once in fill.
// Full-coverage convs (32x32 grid of 4x4 tiles = 1024 threads exact),
// in place: read+FMA -> bar -> write -> bar. 6 barriers total. [best: R13]
// ---------------------------------------------------------------------------
__global__ __launch_bounds__(1024, 8) void k_a(
    const float* __restrict__ x, const float* __restrict__ w1,
    const float* __restrict__ b1, const float* __restrict__ kq,
    const float* __restrict__ beta, float* __restrict__ g)
{
    const int plane = blockIdx.x;          // b*64 + c
    const int c = plane & 63;
    const int tid = threadIdx.x;

    __shared__ __align__(16) float sb[132 * SROW];
    __shared__ float red[16];

    const float* xp = x + (size_t)plane * HH * WW;

    // fill: avgpool(2x2) of x -> interior; margins zero. 132x35 f4.
#pragma unroll
    for (int k = 0; k < 5; k++) {
        int i = tid + k * 1024;
        if (i < 132 * 35) {
            int r = i / 35, f = i % 35;
            int d = 4 * f;
            float4 v = make_float4(0.f, 0.f, 0.f, 0.f);
            int p = r - 2;                 // pooled row
            if (d >= 8 && d < 136 && (unsigned)p < 128u) {
                int xc = 2 * (d - 8);
                const float* p0 = xp + (size_t)(2 * p) * WW + xc;
                const float* p1 = p0 + WW;
                float4 a0 = *(const float4*)p0;
                float4 a1 = *(const float4*)(p0 + 4);
                float4 b0 = *(const float4*)p1;
                float4 b1v = *(const float4*)(p1 + 4);
                v.x = 0.25f * (a0.x + a0.y + b0.x + b0.y);
                v.y = 0.25f * (a0.z + a0.w + b0.z + b0.w);
                v.z = 0.25f * (a1.x + a1.y + b1v.x + b1v.y);
                v.w = 0.25f * (a1.z + a1.w + b1v.z + b1v.w);
            }
            *(float4*)&sb[r * SROW + d] = v;
        }
    }
    __syncthreads();

    const int v = tid >> 5, u = tid & 31;              // 32x32 tiles
    const float* rbA = &sb[(4 * v) * SROW + 4 * u + 4];
    float* wbA = &sb[(4 * v + 2) * SROW + 8 + 4 * u];

    // conv1, conv2 in place
#pragma unroll
    for (int cv = 0; cv < 2; cv++) {
        float w[25];
#pragma unroll
        for (int k = 0; k < 25; k++) w[k] = w1[cv * CC * 25 + c * 25 + k]; // SGPR
        const float bv = b1[cv * CC + c];
        float a[4][4];
        conv4x4_e12<SROW>(rbA, w, bv, a);
        __syncthreads();
#pragma unroll
        for (int i = 0; i < 4; i++)
            *(float4*)(wbA + i * SROW) = make_float4(a[i][0], a[i][1], a[i][2], a[i][3]);
        __syncthreads();
    }

    // conv3 + register 2x2 maxpool + dot with kq
    float partial;
    {
        float w[25];
#pragma unroll
        for (int k = 0; k < 25; k++) w[k] = w1[2 * CC * 25 + c * 25 + k];
        const float bv = b1[2 * CC + c];
        float a[4][4];
        conv4x4_e12<SROW>(rbA, w, bv, a);
        float m00 = fmaxf(fmaxf(a[0][0], a[0][1]), fmaxf(a[1][0], a[1][1]));
        float m01 = fmaxf(fmaxf(a[0][2], a[0][3]), fmaxf(a[1][2], a[1][3]));
        float m10 = fmaxf(fmaxf(a[2][0], a[2][1]), fmaxf(a[3][0], a[3][1]));
        float m11 = fmaxf(fmaxf(a[2][2], a[2][3]), fmaxf(a[3][2], a[3][3]));
        float4 kk = *(const float4*)&kq[((size_t)(c * 32 + v) * 32 + u) * 4];
        partial = m00 * kk.x + m01 * kk.y + m10 * kk.z + m11 * kk.w;
    }
#pragma unroll
    for (int off = 32; off > 0; off >>= 1) partial += __shfl_down(partial, off);
    if ((tid & 63) == 0) red[tid >> 6] = partial;
    __syncthreads();
    if (tid == 0) {
        float t = 0.f;
#pragma unroll
        for (int k = 0; k < 16; k++) t += red[k];
        g[plane] = t + beta[c];
    }
}

// ---------------------------------------------------------------------------
// k_kern: kern[o] = dot(g[b,:], wk[oo,:]) + bk[oo]
// ---------------------------------------------------------------------------
__global__ __launch_bounds__(256) void k_kern(
    const float* __restrict__ g, const float* __restrict__ wk,
    const float* __restrict__ bk, float* __restrict__ kern)
{
    const int o = blockIdx.x * 256 + threadIdx.x;     // 0..12799
    const int b = o / 1600, oo = o - b * 1600;
    float v = bk[oo];
    const float* wp = wk + (size_t)oo * 64;
    const float* gp = g + b * 64;
#pragma unroll 16
    for (int k = 0; k < 64; k++) v += gp[k] * wp[k];
    kern[o] = v;
}

// ---------------------------------------------------------------------------
// k_dyn: dynamic depthwise conv 5x5, 64x64 tile, 4x4 outputs/thread.
// At ~88% of achievable HBM BW (R4/R13 analysis) -- roofline, unchanged.
// ---------------------------------------------------------------------------
__global__ __launch_bounds__(256) void k_dyn(
    const float* __restrict__ x, const float* __restrict__ kern,
    const float* __restrict__ bias, float* __restrict__ out)
{
    const int plane = blockIdx.z;
    const int tx = blockIdx.x, ty = blockIdx.y;
    const int tid = threadIdx.x;

    __shared__ __align__(16) float sx[68 * 76];

    const float* xp = x + (size_t)plane * HH * WW;
    const int R0 = ty * 64, C0 = tx * 64;

#pragma unroll
    for (int k = 0; k < 5; k++) {
        int i = tid + k * 256;
        if (i < 68 * 18) {
            int r = i / 18, q = i - r * 18;
            int gr = R0 - 2 + r;
            int gc = C0 - 4 + 4 * q;
            float4 v = make_float4(0.f, 0.f, 0.f, 0.f);
            if ((unsigned)gr < HH && (unsigned)gc < WW)
                v = *(const float4*)(xp + (size_t)gr * WW + gc);
            *(float4*)&sx[r * 76 + 4 * q] = v;
        }
    }

    float w[25];
#pragma unroll
    for (int k = 0; k < 25; k++) w[k] = kern[(size_t)plane * 25 + k];   // uniform
    const float bv = bias[plane & 63];

    __syncthreads();

    const int tr = (tid >> 4) * 4, tc = (tid & 15) * 4;
    float acc[4][4];
    conv4x4_e12<76>(&sx[tr * 76 + tc], w, bv, acc);

    float* op = out + (size_t)plane * HH * WW + (size_t)(R0 + tr) * WW + C0 + tc;
#pragma unroll
    for (int i = 0; i < 4; i++)
        *(float4*)(op + (size_t)i * WW) = make_float4(acc[i][0], acc[i][1], acc[i][2], acc[i][3]);
}

// ---------------------------------------------------------------------------
extern "C" void kernel_launch(void* const* d_in, const int* in_sizes, int n_in,
                              void* d_out, int out_size, void* d_ws, size_t ws_size,
                              hipStream_t stream)
{
    const float* x    = (const float*)d_in[0];
    const float* w1   = (const float*)d_in[1];
    const float* b1   = (const float*)d_in[2];
    const float* w2   = (const float*)d_in[3];
    const float* b2   = (const float*)d_in[4];
    const float* wk   = (const float*)d_in[5];
    const float* bk   = (const float*)d_in[6];
    const float* bias = (const float*)d_in[7];
    float* out = (float*)d_out;

    float* ws   = (float*)d_ws;
    float* kq   = ws;                       // 64*32*32*4 = 262144 floats
    float* beta = ws + 262144;              // 64
    float* g    = ws + 262208;              // 512
    float* kern = ws + 262720;              // 12800

    k_keff<<<dim3(64), 512, 0, stream>>>(w2, b2, kq, beta);
    k_a<<<dim3(512), 1024, 0, stream>>>(x, w1, b1, kq, beta, g);
    k_kern<<<dim3(50), 256, 0, stream>>>(g, wk, bk, kern);
    k_dyn<<<dim3(4, 4, 512), 256, 0, stream>>>(x, kern, bias, out);
}